// Round 9
// baseline (864.185 us; speedup 1.0000x reference)
//
#include <hip/hip_runtime.h>
#include <hip/hip_bf16.h>
#include <hip/hip_fp16.h>

// Problem dims
#define A_DIM 4608   // C*9 patch-feature rows
#define L_DIM 4096   // (H/3)*(W/3) spatial columns
#define CH    512
#define H_DIM 192
#define W_DIM 192

// GEMM tile
#define BM 128
#define BN 128
#define NSTEP (L_DIM / 16)   // one step = 2 k-planes (k=16), split by half-wave

#define CPB 32       // prep: channels per block

typedef _Float16 half8 __attribute__((ext_vector_type(8)));
typedef float   floatx4 __attribute__((ext_vector_type(4)));
typedef float   floatx16 __attribute__((ext_vector_type(16)));

// ---------------------------------------------------------------------------
// Pass 1: unfold(x) -> k-chunk-major f16 hi/lo split + global sum-of-squares
// accumulation (ss arrays pre-zeroed; block atomicAdds its partials).
// Global layout: U[(l>>3)*A_DIM + a][8] — chunk-major. This layout makes MFMA
// fragments DIRECTLY loadable from global, coalesced (32 rows x 16B dense).
// ---------------------------------------------------------------------------
__global__ __launch_bounds__(256) void prep_kernel(
    const float* __restrict__ x0, const float* __restrict__ x1,
    _Float16* __restrict__ Uhi0, _Float16* __restrict__ Ulo0,
    _Float16* __restrict__ Uhi1, _Float16* __restrict__ Ulo1,
    float* __restrict__ ss0, float* __restrict__ ss1) {
  const int which = blockIdx.z;
  const float* __restrict__ x = which ? x1 : x0;
  _Float16* __restrict__ Uhi = which ? Uhi1 : Uhi0;
  _Float16* __restrict__ Ulo = which ? Ulo1 : Ulo0;
  float* __restrict__ ssg = which ? ss1 : ss0;

  const int ph = blockIdx.y;            // 0..63
  const int c0 = blockIdx.x * CPB;      // channel group base
  const int abase = blockIdx.x * (CPB * 9);

  __shared__ _Float16 sHi[CPB * 9 * 8 * 8];  // 288 rows x 8 chunks x 8 halves
  __shared__ _Float16 sLo[CPB * 9 * 8 * 8];
  __shared__ float ssb[CPB * 9];

  const int t = threadIdx.x;
  for (int a = t; a < CPB * 9; a += 256) ssb[a] = 0.f;
  __syncthreads();

  // ---- phase 1: read input, assemble 16B chunks in regs, stage in LDS
  const int c_l = t >> 3;               // 0..31
  const int s = t & 7;                  // chunk index this thread owns
  const float* __restrict__ rowbase =
      x + ((size_t)(c0 + c_l) * H_DIM + 3 * ph) * W_DIM + s * 24;
  float ssp[9] = {0.f, 0.f, 0.f, 0.f, 0.f, 0.f, 0.f, 0.f, 0.f};

#pragma unroll
  for (int kh = 0; kh < 3; ++kh) {
    const float* __restrict__ rp = rowbase + kh * W_DIM;
    floatx4 v4[6];
#pragma unroll
    for (int i = 0; i < 6; ++i) v4[i] = *(const floatx4*)(rp + i * 4);
    half8 hv[3], lv[3];
#pragma unroll
    for (int i = 0; i < 6; ++i)
#pragma unroll
      for (int j = 0; j < 4; ++j) {
        const int m = i * 4 + j;        // 0..23
        const int kw = m % 3, e = m / 3;
        const float v = v4[i][j];
        ssp[kh * 3 + kw] += v * v;
        const _Float16 h = (_Float16)v;
        hv[kw][e] = h;
        lv[kw][e] = (_Float16)(v - (float)h);
      }
#pragma unroll
    for (int kw = 0; kw < 3; ++kw) {
      const int a_l = c_l * 9 + kh * 3 + kw;
      const int addr = (a_l * 8 + (s ^ (a_l & 7))) * 8;  // XOR-swizzled chunk
      *(half8*)&sHi[addr] = hv[kw];
      *(half8*)&sLo[addr] = lv[kw];
    }
  }
#pragma unroll
  for (int q = 0; q < 9; ++q) atomicAdd(&ssb[c_l * 9 + q], ssp[q]);
  __syncthreads();

  // ---- phase 2: coalesced global writes (consecutive t = consecutive a)
#pragma unroll
  for (int i = 0; i < 9; ++i) {
    const int idx = i * 256 + t;        // 0..2303
    const int c8 = idx / 288;
    const int a_l = idx - c8 * 288;
    const int addr = (a_l * 8 + (c8 ^ (a_l & 7))) * 8;
    const size_t g = ((size_t)(ph * 8 + c8) * A_DIM + abase + a_l) * 8;
    *(half8*)&Uhi[g] = *(const half8*)&sHi[addr];
    *(half8*)&Ulo[g] = *(const half8*)&sLo[addr];
  }
  // ---- global norm accumulation (cross-block over ph)
  for (int a = t; a < CPB * 9; a += 256) atomicAdd(&ssg[abase + a], ssb[a]);
}

// ---------------------------------------------------------------------------
// Pass 2 (NO-LDS register streaming): D[i,j] = sty_i . img_j, 3-term f16
// split, 32x32x16 MFMA, 128x128 block / 64x64 wave tile. Each wave streams
// operand fragments global->VGPR directly (chunk-major layout => 512B-dense
// coalesced loads), register double-buffered: compute step s from buf s&1
// while s+1 is in flight; re-issue s+2 after s's last use. No barriers, no
// LDS, no GLDS -> no phase-locking (R5-R8: pipes summed instead of maxed).
// Steady state vmcnt(8), never drained — the AITER K-loop pattern.
// ---------------------------------------------------------------------------
__global__ __launch_bounds__(256, 2) void gemm_max_kernel(
    const _Float16* __restrict__ Shi, const _Float16* __restrict__ Slo,
    const _Float16* __restrict__ Ihi, const _Float16* __restrict__ Ilo,
    const float* __restrict__ img_ss,
    unsigned long long* __restrict__ packed) {
  const int t = threadIdx.x;
  const int lane = t & 63, wv = t >> 6;
  const int wvr = wv >> 1, wvc = wv & 1;       // 2x2 waves, wave tile 64x64
  const int row0 = blockIdx.y * BM;            // sty rows (i)
  const int col0 = blockIdx.x * BN;            // img rows (j)
  const int l31 = lane & 31, hs = lane >> 5;

  floatx16 acc[2][2];
#pragma unroll
  for (int rf = 0; rf < 2; ++rf)
#pragma unroll
    for (int cf = 0; cf < 2; ++cf) acc[rf][cf] = (floatx16)0.f;

  // Per-lane base addresses (bytes). Step s consumes planes 2s (hs=0) and
  // 2s+1 (hs=1): A[m=l31(+32rf)][k=hs*8+e]. rf=1 is +512B (32 rows x 16B).
  const size_t PLB = (size_t)A_DIM * 16;       // one k-plane, bytes
  const size_t ao = ((size_t)hs * A_DIM + row0 + wvr * 64 + l31) * 16;
  const size_t bo = ((size_t)hs * A_DIM + col0 + wvc * 64 + l31) * 16;
  const char* __restrict__ pAh = (const char*)Shi + ao;
  const char* __restrict__ pAl = (const char*)Slo + ao;
  const char* __restrict__ pBh = (const char*)Ihi + bo;
  const char* __restrict__ pBl = (const char*)Ilo + bo;

  half8 f0[8], f1[8];  // [ah0,ah1,al0,al1,bh0,bh1,bl0,bl1]

#define LOADSTEP(F, s)                                        \
  do {                                                        \
    const size_t o = (size_t)(s) * (2 * PLB);                 \
    F[0] = *(const half8*)(pAh + o);                          \
    F[1] = *(const half8*)(pAh + o + 512);                    \
    F[2] = *(const half8*)(pAl + o);                          \
    F[3] = *(const half8*)(pAl + o + 512);                    \
    F[4] = *(const half8*)(pBh + o);                          \
    F[5] = *(const half8*)(pBh + o + 512);                    \
    F[6] = *(const half8*)(pBl + o);                          \
    F[7] = *(const half8*)(pBl + o + 512);                    \
  } while (0)

#define MFMASTEP(F)                                                         \
  do {                                                                      \
    acc[0][0] = __builtin_amdgcn_mfma_f32_32x32x16_f16(F[0], F[4], acc[0][0], 0, 0, 0); \
    acc[0][1] = __builtin_amdgcn_mfma_f32_32x32x16_f16(F[0], F[5], acc[0][1], 0, 0, 0); \
    acc[1][0] = __builtin_amdgcn_mfma_f32_32x32x16_f16(F[1], F[4], acc[1][0], 0, 0, 0); \
    acc[1][1] = __builtin_amdgcn_mfma_f32_32x32x16_f16(F[1], F[5], acc[1][1], 0, 0, 0); \
    acc[0][0] = __builtin_amdgcn_mfma_f32_32x32x16_f16(F[0], F[6], acc[0][0], 0, 0, 0); \
    acc[0][1] = __builtin_amdgcn_mfma_f32_32x32x16_f16(F[0], F[7], acc[0][1], 0, 0, 0); \
    acc[1][0] = __builtin_amdgcn_mfma_f32_32x32x16_f16(F[1], F[6], acc[1][0], 0, 0, 0); \
    acc[1][1] = __builtin_amdgcn_mfma_f32_32x32x16_f16(F[1], F[7], acc[1][1], 0, 0, 0); \
    acc[0][0] = __builtin_amdgcn_mfma_f32_32x32x16_f16(F[2], F[4], acc[0][0], 0, 0, 0); \
    acc[0][1] = __builtin_amdgcn_mfma_f32_32x32x16_f16(F[2], F[5], acc[0][1], 0, 0, 0); \
    acc[1][0] = __builtin_amdgcn_mfma_f32_32x32x16_f16(F[3], F[4], acc[1][0], 0, 0, 0); \
    acc[1][1] = __builtin_amdgcn_mfma_f32_32x32x16_f16(F[3], F[5], acc[1][1], 0, 0, 0); \
  } while (0)

  LOADSTEP(f0, 0);
  LOADSTEP(f1, 1);
  for (int s = 0; s < NSTEP; s += 2) {
    MFMASTEP(f0);
    if (s + 2 < NSTEP) LOADSTEP(f0, s + 2);
    MFMASTEP(f1);
    if (s + 3 < NSTEP) LOADSTEP(f1, s + 3);
  }

  // Epilogue: v[i,j] = rsqrt(img_ss[i]) * D[i,j]; column max+argmax
  // (first-index wins). 32x32 C/D: col=lane&31, row=(reg&3)+8*(reg>>2)+4*hs.
  float nrv[2][16];
#pragma unroll
  for (int rf = 0; rf < 2; ++rf) {
    const int base_i = row0 + wvr * 64 + rf * 32 + 4 * hs;
#pragma unroll
    for (int g = 0; g < 4; ++g) {
      const floatx4 s4 = *(const floatx4*)&img_ss[base_i + 8 * g];
#pragma unroll
      for (int r = 0; r < 4; ++r) nrv[rf][g * 4 + r] = 1.0f / sqrtf(s4[r]);
    }
  }
#pragma unroll
  for (int cf = 0; cf < 2; ++cf) {
    const int j = col0 + wvc * 64 + cf * 32 + l31;
    float best = -3.4e38f;
    int bi = 0x7FFFFFFF;
#pragma unroll
    for (int rf = 0; rf < 2; ++rf) {
      const int base_i = row0 + wvr * 64 + rf * 32 + 4 * hs;
#pragma unroll
      for (int g = 0; g < 4; ++g)
#pragma unroll
        for (int r = 0; r < 4; ++r) {
          const int i = base_i + 8 * g + r;
          const float v = acc[rf][cf][g * 4 + r] * nrv[rf][g * 4 + r];
          if (v > best) { best = v; bi = i; }  // ascending i => first wins
        }
    }
    const float ov = __shfl_xor(best, 32, 64);
    const int oi = __shfl_xor(bi, 32, 64);
    if (ov > best || (ov == best && oi < bi)) { best = ov; bi = oi; }
    if (hs == 0) {
      const unsigned u = __float_as_uint(best);
      const unsigned key = (u & 0x80000000u) ? ~u : (u | 0x80000000u);
      const unsigned long long pk =
          ((unsigned long long)key << 32) | (unsigned)(~(unsigned)bi);
      atomicMax(&packed[j], pk);
    }
  }
}

// ---------------------------------------------------------------------------
// Pass 3: decode packed, apply rsqrt(sty_ss[j]); out[0..A)=nearest,
// out[A..2A)=max_sim.
// ---------------------------------------------------------------------------
__global__ __launch_bounds__(256) void finalize_kernel(
    const unsigned long long* __restrict__ packed,
    const float* __restrict__ sty_ss, float* __restrict__ out) {
  const int j = blockIdx.x * 256 + threadIdx.x;
  if (j >= A_DIM) return;
  const unsigned long long p = packed[j];
  const unsigned key = (unsigned)(p >> 32);
  const unsigned u = (key & 0x80000000u) ? (key ^ 0x80000000u) : ~key;
  const float v = __uint_as_float(u);
  const int idx = (int)(~(unsigned)(p & 0xFFFFFFFFu));
  out[j] = (float)idx;
  out[A_DIM + j] = v * (1.0f / sqrtf(sty_ss[j]));
}

extern "C" void kernel_launch(void* const* d_in, const int* in_sizes, int n_in,
                              void* d_out, int out_size, void* d_ws, size_t ws_size,
                              hipStream_t stream) {
  const float* model = (const float*)d_in[0];  // img side
  const float* style = (const float*)d_in[1];  // sty side
  float* out = (float*)d_out;
  char* ws = (char*)d_ws;

  const size_t usz = (size_t)A_DIM * L_DIM * 2;  // one f16 matrix: 37,748,736 B
  _Float16* img_hi = (_Float16*)(ws);
  _Float16* img_lo = (_Float16*)(ws + usz);
  _Float16* sty_hi = (_Float16*)(ws + 2 * usz);
  _Float16* sty_lo = (_Float16*)(ws + 3 * usz);
  float* img_ss = (float*)(ws + 4 * usz);        // zeroed accumulators
  float* sty_ss = img_ss + A_DIM;
  unsigned long long* packed = (unsigned long long*)(img_ss + 2 * A_DIM);

  // zero ss accumulators (2*A*4 B) + packed (A*8 B) in one contiguous memset
  hipMemsetAsync(img_ss, 0, (size_t)A_DIM * 16, stream);
  prep_kernel<<<dim3(CH / CPB, H_DIM / 3, 2), 256, 0, stream>>>(
      model, style, img_hi, img_lo, sty_hi, sty_lo, img_ss, sty_ss);
  gemm_max_kernel<<<dim3(A_DIM / BN, A_DIM / BM), 256, 0, stream>>>(
      sty_hi, sty_lo, img_hi, img_lo, img_ss, packed);
  finalize_kernel<<<18, 256, 0, stream>>>(packed, sty_ss, out);
}

// Round 10
// 771.738 us; speedup vs baseline: 1.1198x; 1.1198x over previous
//
#include <hip/hip_runtime.h>
#include <hip/hip_bf16.h>
#include <hip/hip_fp16.h>

// Problem dims
#define A_DIM 4608   // C*9 patch-feature rows
#define L_DIM 4096   // (H/3)*(W/3) spatial columns
#define CH    512
#define H_DIM 192
#define W_DIM 192

// GEMM tile
#define BM 256       // sty rows per block (4 waves x 128x64 wave tiles)
#define BN 128       // img rows per block
#define BK 16        // 2 kchunks (planes) of 8 halves per stage
#define NS (L_DIM / BK)

#define CPB 32       // prep: channels per block

typedef _Float16 half8 __attribute__((ext_vector_type(8)));
typedef float   floatx4 __attribute__((ext_vector_type(4)));
typedef float   floatx16 __attribute__((ext_vector_type(16)));

// ---------------------------------------------------------------------------
// Pass 1: unfold(x) -> k-chunk-major f16 hi/lo split + global sum-of-squares
// accumulation (ss arrays pre-zeroed; block atomicAdds its partials).
// Global layout: U[(l>>3)*A_DIM + a][8] (chunk-major; GEMM staging contiguous
// and conflict-free — verified R4/R5/R7/R8: GEMM SQ_LDS_BANK_CONFLICT = 0).
// ---------------------------------------------------------------------------
__global__ __launch_bounds__(256) void prep_kernel(
    const float* __restrict__ x0, const float* __restrict__ x1,
    _Float16* __restrict__ Uhi0, _Float16* __restrict__ Ulo0,
    _Float16* __restrict__ Uhi1, _Float16* __restrict__ Ulo1,
    float* __restrict__ ss0, float* __restrict__ ss1) {
  const int which = blockIdx.z;
  const float* __restrict__ x = which ? x1 : x0;
  _Float16* __restrict__ Uhi = which ? Uhi1 : Uhi0;
  _Float16* __restrict__ Ulo = which ? Ulo1 : Ulo0;
  float* __restrict__ ssg = which ? ss1 : ss0;

  const int ph = blockIdx.y;            // 0..63
  const int c0 = blockIdx.x * CPB;      // channel group base
  const int abase = blockIdx.x * (CPB * 9);

  __shared__ _Float16 sHi[CPB * 9 * 8 * 8];  // 288 rows x 8 chunks x 8 halves
  __shared__ _Float16 sLo[CPB * 9 * 8 * 8];
  __shared__ float ssb[CPB * 9];

  const int t = threadIdx.x;
  for (int a = t; a < CPB * 9; a += 256) ssb[a] = 0.f;
  __syncthreads();

  // ---- phase 1: read input, assemble 16B chunks in regs, stage in LDS
  const int c_l = t >> 3;               // 0..31
  const int s = t & 7;                  // chunk index this thread owns
  const float* __restrict__ rowbase =
      x + ((size_t)(c0 + c_l) * H_DIM + 3 * ph) * W_DIM + s * 24;
  float ssp[9] = {0.f, 0.f, 0.f, 0.f, 0.f, 0.f, 0.f, 0.f, 0.f};

#pragma unroll
  for (int kh = 0; kh < 3; ++kh) {
    const float* __restrict__ rp = rowbase + kh * W_DIM;
    floatx4 v4[6];
#pragma unroll
    for (int i = 0; i < 6; ++i) v4[i] = *(const floatx4*)(rp + i * 4);
    half8 hv[3], lv[3];
#pragma unroll
    for (int i = 0; i < 6; ++i)
#pragma unroll
      for (int j = 0; j < 4; ++j) {
        const int m = i * 4 + j;        // 0..23
        const int kw = m % 3, e = m / 3;
        const float v = v4[i][j];
        ssp[kh * 3 + kw] += v * v;
        const _Float16 h = (_Float16)v;
        hv[kw][e] = h;
        lv[kw][e] = (_Float16)(v - (float)h);
      }
#pragma unroll
    for (int kw = 0; kw < 3; ++kw) {
      const int a_l = c_l * 9 + kh * 3 + kw;
      const int addr = (a_l * 8 + (s ^ (a_l & 7))) * 8;  // XOR-swizzled chunk
      *(half8*)&sHi[addr] = hv[kw];
      *(half8*)&sLo[addr] = lv[kw];
    }
  }
#pragma unroll
  for (int q = 0; q < 9; ++q) atomicAdd(&ssb[c_l * 9 + q], ssp[q]);
  __syncthreads();

  // ---- phase 2: coalesced global writes (consecutive t = consecutive a)
#pragma unroll
  for (int i = 0; i < 9; ++i) {
    const int idx = i * 256 + t;        // 0..2303
    const int c8 = idx / 288;
    const int a_l = idx - c8 * 288;
    const int addr = (a_l * 8 + (c8 ^ (a_l & 7))) * 8;
    const size_t g = ((size_t)(ph * 8 + c8) * A_DIM + abase + a_l) * 8;
    *(half8*)&Uhi[g] = *(const half8*)&sHi[addr];
    *(half8*)&Ulo[g] = *(const half8*)&sLo[addr];
  }
  // ---- global norm accumulation (cross-block over ph)
  for (int a = t; a < CPB * 9; a += 256) atomicAdd(&ssg[abase + a], ssb[a]);
}

// ---------------------------------------------------------------------------
// Pass 2: D[i,j] = sty_i . img_j, 3-term f16 split, 32x32x16 MFMA.
// 256x128 block / 128x64 wave tiles (4 waves), BK=16, double-buffered LDS,
// R5-proven loop order (ISSUE(ks+1) -> vmcnt(6) -> barrier -> compute ->
// barrier; VMEM queue never drained across a barrier — R7 lesson).
// vs R5: LDS reads 0.67 -> 0.5 KB/MFMA, GLDS writes 0.33 -> 0.25 KB/MFMA.
// ---------------------------------------------------------------------------
#define GLDS(g, l)                                                          \
  __builtin_amdgcn_global_load_lds(                                        \
      (const __attribute__((address_space(1))) void*)(g),                   \
      (__attribute__((address_space(3))) void*)(l), 16, 0, 0)

__global__ __launch_bounds__(256, 2) void gemm_max_kernel(
    const _Float16* __restrict__ Shi, const _Float16* __restrict__ Slo,
    const _Float16* __restrict__ Ihi, const _Float16* __restrict__ Ilo,
    const float* __restrict__ img_ss,
    unsigned long long* __restrict__ packed) {
  // per buffer: A planes [2][256 rows][8], B planes [2][128 rows][8]. 48 KB.
  __shared__ _Float16 sAh[2][4096];
  __shared__ _Float16 sAl[2][4096];
  __shared__ _Float16 sBh[2][2048];
  __shared__ _Float16 sBl[2][2048];

  const int t = threadIdx.x;
  const int lane = t & 63, wv = t >> 6;
  const int wvr = wv >> 1, wvc = wv & 1;       // 2x2 waves, wave tile 128x64
  const int row0 = blockIdx.y * BM;            // sty rows (i)
  const int col0 = blockIdx.x * BN;            // img rows (j)
  const int l31 = lane & 31, hs = lane >> 5;

  floatx16 acc[4][2];
#pragma unroll
  for (int rf = 0; rf < 4; ++rf)
#pragma unroll
    for (int cf = 0; cf < 2; ++cf) acc[rf][cf] = (floatx16)0.f;

  // Staging: A -> thread t covers row t in both planes (2 GLDS each for h/l);
  // B -> thread t covers (plane t>>7, row t&127), 1 GLDS each for h/l.
  // All LDS dests are t*16B (wave-uniform base + lane*16, GLDS-legal).
  const size_t CH8 = (size_t)A_DIM * 8;        // one kchunk plane, in halves
  const size_t soA = (size_t)t * 8;
  const size_t soB = (size_t)(t & 127) * 8 + (size_t)(t >> 7) * CH8;
  const _Float16* __restrict__ pAh = Shi + (size_t)row0 * 8 + soA;
  const _Float16* __restrict__ pAl = Slo + (size_t)row0 * 8 + soA;
  const _Float16* __restrict__ pBh = Ihi + (size_t)col0 * 8 + soB;
  const _Float16* __restrict__ pBl = Ilo + (size_t)col0 * 8 + soB;
  const int dl = t * 8;  // halves == t*16 bytes

#define ISSUE(b, off)                                      \
  do {                                                     \
    GLDS(pAh + (off),       &sAh[b][dl]);                  \
    GLDS(pAh + (off) + CH8, &sAh[b][dl + 2048]);           \
    GLDS(pAl + (off),       &sAl[b][dl]);                  \
    GLDS(pAl + (off) + CH8, &sAl[b][dl + 2048]);           \
    GLDS(pBh + (off),       &sBh[b][dl]);                  \
    GLDS(pBl + (off),       &sBl[b][dl]);                  \
  } while (0)

  ISSUE(0, 0);  // prologue prefetch of stage 0

  for (int ks = 0; ks < NS; ++ks) {
    const int cur = ks & 1;
    if (ks + 1 < NS) {
      ISSUE(1 - cur, (size_t)(ks + 1) * 2 * CH8);
      asm volatile("s_waitcnt vmcnt(6)" ::: "memory");  // stage ks complete
    } else {
      asm volatile("s_waitcnt vmcnt(0)" ::: "memory");
    }
    asm volatile("s_barrier" ::: "memory");  // all waves' stage-ks data in LDS

    // kchunk (plane) this lane-half consumes: hs. A[m][k=hs*8+e].
    half8 ah[4], al[4], bh[2], bl[2];
#pragma unroll
    for (int rf = 0; rf < 4; ++rf) {
      const int idx = (hs * 256 + wvr * 128 + rf * 32 + l31) * 8;
      ah[rf] = *(const half8*)&sAh[cur][idx];
      al[rf] = *(const half8*)&sAl[cur][idx];
    }
#pragma unroll
    for (int cf = 0; cf < 2; ++cf) {
      const int idx = (hs * 128 + wvc * 64 + cf * 32 + l31) * 8;
      bh[cf] = *(const half8*)&sBh[cur][idx];
      bl[cf] = *(const half8*)&sBl[cur][idx];
    }
    // term-major order: 8 independent MFMAs between same-acc reuses
#pragma unroll
    for (int rf = 0; rf < 4; ++rf)
#pragma unroll
      for (int cf = 0; cf < 2; ++cf)
        acc[rf][cf] = __builtin_amdgcn_mfma_f32_32x32x16_f16(
            ah[rf], bh[cf], acc[rf][cf], 0, 0, 0);
#pragma unroll
    for (int rf = 0; rf < 4; ++rf)
#pragma unroll
      for (int cf = 0; cf < 2; ++cf)
        acc[rf][cf] = __builtin_amdgcn_mfma_f32_32x32x16_f16(
            ah[rf], bl[cf], acc[rf][cf], 0, 0, 0);
#pragma unroll
    for (int rf = 0; rf < 4; ++rf)
#pragma unroll
      for (int cf = 0; cf < 2; ++cf)
        acc[rf][cf] = __builtin_amdgcn_mfma_f32_32x32x16_f16(
            al[rf], bh[cf], acc[rf][cf], 0, 0, 0);

    asm volatile("s_barrier" ::: "memory");  // reads done before overwrite
  }

  // Epilogue: v[i,j] = rsqrt(img_ss[i]) * D[i,j]; column max+argmax
  // (first-index wins). 32x32 C/D: col=lane&31, row=(reg&3)+8*(reg>>2)+4*hs.
#pragma unroll
  for (int cf = 0; cf < 2; ++cf) {
    const int j = col0 + wvc * 64 + cf * 32 + l31;
    float best = -3.4e38f;
    int bi = 0x7FFFFFFF;
#pragma unroll
    for (int rf = 0; rf < 4; ++rf) {
      const int base_i = row0 + wvr * 128 + rf * 32 + 4 * hs;
#pragma unroll
      for (int g = 0; g < 4; ++g) {
        const floatx4 s4 = *(const floatx4*)&img_ss[base_i + 8 * g];
#pragma unroll
        for (int r = 0; r < 4; ++r) {
          const int i = base_i + 8 * g + r;
          const float v = acc[rf][cf][g * 4 + r] * (1.0f / sqrtf(s4[r]));
          if (v > best) { best = v; bi = i; }  // ascending i => first wins
        }
      }
    }
    const float ov = __shfl_xor(best, 32, 64);
    const int oi = __shfl_xor(bi, 32, 64);
    if (ov > best || (ov == best && oi < bi)) { best = ov; bi = oi; }
    if (hs == 0) {
      const unsigned u = __float_as_uint(best);
      const unsigned key = (u & 0x80000000u) ? ~u : (u | 0x80000000u);
      const unsigned long long pk =
          ((unsigned long long)key << 32) | (unsigned)(~(unsigned)bi);
      atomicMax(&packed[j], pk);
    }
  }
}

// ---------------------------------------------------------------------------
// Pass 3: decode packed, apply rsqrt(sty_ss[j]); out[0..A)=nearest,
// out[A..2A)=max_sim.
// ---------------------------------------------------------------------------
__global__ __launch_bounds__(256) void finalize_kernel(
    const unsigned long long* __restrict__ packed,
    const float* __restrict__ sty_ss, float* __restrict__ out) {
  const int j = blockIdx.x * 256 + threadIdx.x;
  if (j >= A_DIM) return;
  const unsigned long long p = packed[j];
  const unsigned key = (unsigned)(p >> 32);
  const unsigned u = (key & 0x80000000u) ? (key ^ 0x80000000u) : ~key;
  const float v = __uint_as_float(u);
  const int idx = (int)(~(unsigned)(p & 0xFFFFFFFFu));
  out[j] = (float)idx;
  out[A_DIM + j] = v * (1.0f / sqrtf(sty_ss[j]));
}

extern "C" void kernel_launch(void* const* d_in, const int* in_sizes, int n_in,
                              void* d_out, int out_size, void* d_ws, size_t ws_size,
                              hipStream_t stream) {
  const float* model = (const float*)d_in[0];  // img side
  const float* style = (const float*)d_in[1];  // sty side
  float* out = (float*)d_out;
  char* ws = (char*)d_ws;

  const size_t usz = (size_t)A_DIM * L_DIM * 2;  // one f16 matrix: 37,748,736 B
  _Float16* img_hi = (_Float16*)(ws);
  _Float16* img_lo = (_Float16*)(ws + usz);
  _Float16* sty_hi = (_Float16*)(ws + 2 * usz);
  _Float16* sty_lo = (_Float16*)(ws + 3 * usz);
  float* img_ss = (float*)(ws + 4 * usz);        // zeroed accumulators
  float* sty_ss = img_ss + A_DIM;
  unsigned long long* packed = (unsigned long long*)(img_ss + 2 * A_DIM);

  // zero ss accumulators (2*A*4 B) + packed (A*8 B) in one contiguous memset
  hipMemsetAsync(img_ss, 0, (size_t)A_DIM * 16, stream);
  prep_kernel<<<dim3(CH / CPB, H_DIM / 3, 2), 256, 0, stream>>>(
      model, style, img_hi, img_lo, sty_hi, sty_lo, img_ss, sty_ss);
  gemm_max_kernel<<<dim3(A_DIM / BN, A_DIM / BM), 256, 0, stream>>>(
      sty_hi, sty_lo, img_hi, img_lo, img_ss, packed);
  finalize_kernel<<<18, 256, 0, stream>>>(packed, sty_ss, out);
}

// Round 11
// 764.379 us; speedup vs baseline: 1.1306x; 1.0096x over previous
//
#include <hip/hip_runtime.h>
#include <hip/hip_bf16.h>
#include <hip/hip_fp16.h>

// Problem dims
#define A_DIM 4608   // C*9 patch-feature rows
#define L_DIM 4096   // (H/3)*(W/3) spatial columns
#define CH    512
#define H_DIM 192
#define W_DIM 192

// GEMM tile
#define BM 128
#define BN 128
#define BK 32        // 4 kchunks (planes) of 8 halves per stage
#define NS (L_DIM / BK)

#define CPB 32       // prep: channels per block

typedef _Float16 half8 __attribute__((ext_vector_type(8)));
typedef float   floatx4 __attribute__((ext_vector_type(4)));
typedef float   floatx16 __attribute__((ext_vector_type(16)));

// ---------------------------------------------------------------------------
// Pass 1: unfold(x) -> k-chunk-major f16 hi/lo split + global sum-of-squares
// accumulation (ss arrays pre-zeroed; block atomicAdds its partials).
// Global layout: U[(l>>3)*A_DIM + a][8] (chunk-major: GEMM B-staging is
// contiguous+conflict-free, and A-fragments are directly loadable from
// global as 512B-dense runs per half-wave).
// ---------------------------------------------------------------------------
__global__ __launch_bounds__(256) void prep_kernel(
    const float* __restrict__ x0, const float* __restrict__ x1,
    _Float16* __restrict__ Uhi0, _Float16* __restrict__ Ulo0,
    _Float16* __restrict__ Uhi1, _Float16* __restrict__ Ulo1,
    float* __restrict__ ss0, float* __restrict__ ss1) {
  const int which = blockIdx.z;
  const float* __restrict__ x = which ? x1 : x0;
  _Float16* __restrict__ Uhi = which ? Uhi1 : Uhi0;
  _Float16* __restrict__ Ulo = which ? Ulo1 : Ulo0;
  float* __restrict__ ssg = which ? ss1 : ss0;

  const int ph = blockIdx.y;            // 0..63
  const int c0 = blockIdx.x * CPB;      // channel group base
  const int abase = blockIdx.x * (CPB * 9);

  __shared__ _Float16 sHi[CPB * 9 * 8 * 8];  // 288 rows x 8 chunks x 8 halves
  __shared__ _Float16 sLo[CPB * 9 * 8 * 8];
  __shared__ float ssb[CPB * 9];

  const int t = threadIdx.x;
  for (int a = t; a < CPB * 9; a += 256) ssb[a] = 0.f;
  __syncthreads();

  // ---- phase 1: read input, assemble 16B chunks in regs, stage in LDS
  const int c_l = t >> 3;               // 0..31
  const int s = t & 7;                  // chunk index this thread owns
  const float* __restrict__ rowbase =
      x + ((size_t)(c0 + c_l) * H_DIM + 3 * ph) * W_DIM + s * 24;
  float ssp[9] = {0.f, 0.f, 0.f, 0.f, 0.f, 0.f, 0.f, 0.f, 0.f};

#pragma unroll
  for (int kh = 0; kh < 3; ++kh) {
    const float* __restrict__ rp = rowbase + kh * W_DIM;
    floatx4 v4[6];
#pragma unroll
    for (int i = 0; i < 6; ++i) v4[i] = *(const floatx4*)(rp + i * 4);
    half8 hv[3], lv[3];
#pragma unroll
    for (int i = 0; i < 6; ++i)
#pragma unroll
      for (int j = 0; j < 4; ++j) {
        const int m = i * 4 + j;        // 0..23
        const int kw = m % 3, e = m / 3;
        const float v = v4[i][j];
        ssp[kh * 3 + kw] += v * v;
        const _Float16 h = (_Float16)v;
        hv[kw][e] = h;
        lv[kw][e] = (_Float16)(v - (float)h);
      }
#pragma unroll
    for (int kw = 0; kw < 3; ++kw) {
      const int a_l = c_l * 9 + kh * 3 + kw;
      const int addr = (a_l * 8 + (s ^ (a_l & 7))) * 8;  // XOR-swizzled chunk
      *(half8*)&sHi[addr] = hv[kw];
      *(half8*)&sLo[addr] = lv[kw];
    }
  }
#pragma unroll
  for (int q = 0; q < 9; ++q) atomicAdd(&ssb[c_l * 9 + q], ssp[q]);
  __syncthreads();

  // ---- phase 2: coalesced global writes (consecutive t = consecutive a)
#pragma unroll
  for (int i = 0; i < 9; ++i) {
    const int idx = i * 256 + t;        // 0..2303
    const int c8 = idx / 288;
    const int a_l = idx - c8 * 288;
    const int addr = (a_l * 8 + (c8 ^ (a_l & 7))) * 8;
    const size_t g = ((size_t)(ph * 8 + c8) * A_DIM + abase + a_l) * 8;
    *(half8*)&Uhi[g] = *(const half8*)&sHi[addr];
    *(half8*)&Ulo[g] = *(const half8*)&sLo[addr];
  }
  // ---- global norm accumulation (cross-block over ph)
  for (int a = t; a < CPB * 9; a += 256) atomicAdd(&ssg[abase + a], ssb[a]);
}

// ---------------------------------------------------------------------------
// Pass 2 (HYBRID): D[i,j] = sty_i . img_j, 3-term f16 split, 32x32x16 MFMA,
// 128x128 tile / 64x64 wave tiles, BK=32.
// B (img) staged via GLDS double-buffered LDS (R5-proven loop; VMEM queue
// never drained across barriers). A (sty) loaded DIRECTLY global->VGPR,
// register-double-buffered 2 stages ahead. LDS traffic halves vs R5
// (96 -> 48 KB/block-stage -> 2 cyc/MFMA = matrix-pipe rate); A rides the
// L1/L2 path (wvc-pair reuse is L1-local). Steady state: 12 loads in flight
// (4 B-GLDS + 8 A-loads), s_waitcnt vmcnt(12).
// ---------------------------------------------------------------------------
#define GLDS(g, l)                                                          \
  __builtin_amdgcn_global_load_lds(                                        \
      (const __attribute__((address_space(1))) void*)(g),                   \
      (__attribute__((address_space(3))) void*)(l), 16, 0, 0)

__global__ __launch_bounds__(256, 2) void gemm_max_kernel(
    const _Float16* __restrict__ Shi, const _Float16* __restrict__ Slo,
    const _Float16* __restrict__ Ihi, const _Float16* __restrict__ Ilo,
    const float* __restrict__ img_ss,
    unsigned long long* __restrict__ packed) {
  // B buffers only: [buf][plane(4) x 128 rows x 8 halves] = 8 KB each.
  __shared__ _Float16 sBh[2][4096];
  __shared__ _Float16 sBl[2][4096];

  const int t = threadIdx.x;
  const int lane = t & 63, wv = t >> 6;
  const int wvr = wv >> 1, wvc = wv & 1;       // 2x2 waves, wave tile 64x64
  const int row0 = blockIdx.y * BM;            // sty rows (i)
  const int col0 = blockIdx.x * BN;            // img rows (j)
  const int l31 = lane & 31, hs = lane >> 5;

  floatx16 acc[2][2];
#pragma unroll
  for (int rf = 0; rf < 2; ++rf)
#pragma unroll
    for (int cf = 0; cf < 2; ++cf) acc[rf][cf] = (floatx16)0.f;

  const size_t CH8 = (size_t)A_DIM * 8;        // one kchunk plane, in halves

  // B staging: thread t covers (plane t>>7, row t&127); planes {0,1} via
  // first GLDS, {2,3} via +2*CH8. LDS dest t*16B (wave-uniform+lane*16).
  const size_t soB = (size_t)(t & 127) * 8 + (size_t)(t >> 7) * CH8;
  const _Float16* __restrict__ pBh = Ihi + (size_t)col0 * 8 + soB;
  const _Float16* __restrict__ pBl = Ilo + (size_t)col0 * 8 + soB;
  const int dl = t * 8;  // halves == t*16 bytes

  // A direct-load bases: lane address for (rf, kk): plane kc = kk*2+hs,
  // row = row0 + wvr*64 + rf*32 + l31. Per half-wave: 512B dense.
  const _Float16* __restrict__ pAh =
      Shi + ((size_t)(row0 + wvr * 64 + l31)) * 8 + (size_t)hs * CH8;
  const _Float16* __restrict__ pAl =
      Slo + ((size_t)(row0 + wvr * 64 + l31)) * 8 + (size_t)hs * CH8;

  half8 fa0[8], fa1[8];  // [kk*4 + {ah0,ah1,al0,al1}] per buffer

#define BISSUE(b, s)                                       \
  do {                                                     \
    const size_t o = (size_t)(s) * 4 * CH8;                \
    GLDS(pBh + o,           &sBh[b][dl]);                  \
    GLDS(pBh + o + 2 * CH8, &sBh[b][dl + 2048]);           \
    GLDS(pBl + o,           &sBl[b][dl]);                  \
    GLDS(pBl + o + 2 * CH8, &sBl[b][dl + 2048]);           \
  } while (0)

#define ALOAD(F, s)                                        \
  do {                                                     \
    const size_t o = (size_t)(s) * 4 * CH8;                \
    F[0] = *(const half8*)(pAh + o);                       \
    F[1] = *(const half8*)(pAh + o + 256);                 \
    F[2] = *(const half8*)(pAl + o);                       \
    F[3] = *(const half8*)(pAl + o + 256);                 \
    F[4] = *(const half8*)(pAh + o + 2 * CH8);             \
    F[5] = *(const half8*)(pAh + o + 2 * CH8 + 256);       \
    F[6] = *(const half8*)(pAl + o + 2 * CH8);             \
    F[7] = *(const half8*)(pAl + o + 2 * CH8 + 256);       \
  } while (0)

#define MFMA(a, b, c) __builtin_amdgcn_mfma_f32_32x32x16_f16(a, b, c, 0, 0, 0)

#define COMPUTE(F, b)                                                       \
  do {                                                                      \
    _Pragma("unroll")                                                       \
    for (int kk = 0; kk < 2; ++kk) {                                        \
      const int kc = kk * 2 + hs;                                           \
      half8 bh[2], bl[2];                                                   \
      _Pragma("unroll")                                                     \
      for (int cf = 0; cf < 2; ++cf) {                                      \
        const int idx = (kc * 128 + wvc * 64 + cf * 32 + l31) * 8;          \
        bh[cf] = *(const half8*)&sBh[b][idx];                               \
        bl[cf] = *(const half8*)&sBl[b][idx];                               \
      }                                                                     \
      acc[0][0] = MFMA(F[kk * 4 + 0], bh[0], acc[0][0]);                    \
      acc[0][1] = MFMA(F[kk * 4 + 0], bh[1], acc[0][1]);                    \
      acc[1][0] = MFMA(F[kk * 4 + 1], bh[0], acc[1][0]);                    \
      acc[1][1] = MFMA(F[kk * 4 + 1], bh[1], acc[1][1]);                    \
      acc[0][0] = MFMA(F[kk * 4 + 0], bl[0], acc[0][0]);                    \
      acc[0][1] = MFMA(F[kk * 4 + 0], bl[1], acc[0][1]);                    \
      acc[1][0] = MFMA(F[kk * 4 + 1], bl[0], acc[1][0]);                    \
      acc[1][1] = MFMA(F[kk * 4 + 1], bl[1], acc[1][1]);                    \
      acc[0][0] = MFMA(F[kk * 4 + 2], bh[0], acc[0][0]);                    \
      acc[0][1] = MFMA(F[kk * 4 + 2], bh[1], acc[0][1]);                    \
      acc[1][0] = MFMA(F[kk * 4 + 3], bh[0], acc[1][0]);                    \
      acc[1][1] = MFMA(F[kk * 4 + 3], bh[1], acc[1][1]);                    \
    }                                                                       \
  } while (0)

#define STAGE(F, b, s)                                                      \
  do {                                                                      \
    if ((s) + 1 < NS)                                                       \
      asm volatile("s_waitcnt vmcnt(12)" ::: "memory");                     \
    else                                                                    \
      asm volatile("s_waitcnt vmcnt(0)" ::: "memory");                      \
    asm volatile("s_barrier" ::: "memory");                                 \
    COMPUTE(F, b);                                                          \
    asm volatile("s_barrier" ::: "memory");                                 \
    if ((s) + 2 < NS) { BISSUE(b, (s) + 2); ALOAD(F, (s) + 2); }            \
  } while (0)

  BISSUE(0, 0); ALOAD(fa0, 0);
  BISSUE(1, 1); ALOAD(fa1, 1);
  for (int ks = 0; ks < NS; ks += 2) {
    STAGE(fa0, 0, ks);
    STAGE(fa1, 1, ks + 1);
  }

  // Epilogue: v[i,j] = rsqrt(img_ss[i]) * D[i,j]; column max+argmax
  // (first-index wins). 32x32 C/D: col=lane&31, row=(reg&3)+8*(reg>>2)+4*hs.
#pragma unroll
  for (int cf = 0; cf < 2; ++cf) {
    const int j = col0 + wvc * 64 + cf * 32 + l31;
    float best = -3.4e38f;
    int bi = 0x7FFFFFFF;
#pragma unroll
    for (int rf = 0; rf < 2; ++rf) {
      const int base_i = row0 + wvr * 64 + rf * 32 + 4 * hs;
#pragma unroll
      for (int g = 0; g < 4; ++g) {
        const floatx4 s4 = *(const floatx4*)&img_ss[base_i + 8 * g];
#pragma unroll
        for (int r = 0; r < 4; ++r) {
          const int i = base_i + 8 * g + r;
          const float v = acc[rf][cf][g * 4 + r] * (1.0f / sqrtf(s4[r]));
          if (v > best) { best = v; bi = i; }  // ascending i => first wins
        }
      }
    }
    const float ov = __shfl_xor(best, 32, 64);
    const int oi = __shfl_xor(bi, 32, 64);
    if (ov > best || (ov == best && oi < bi)) { best = ov; bi = oi; }
    if (hs == 0) {
      const unsigned u = __float_as_uint(best);
      const unsigned key = (u & 0x80000000u) ? ~u : (u | 0x80000000u);
      const unsigned long long pk =
          ((unsigned long long)key << 32) | (unsigned)(~(unsigned)bi);
      atomicMax(&packed[j], pk);
    }
  }
}

// ---------------------------------------------------------------------------
// Pass 3: decode packed, apply rsqrt(sty_ss[j]); out[0..A)=nearest,
// out[A..2A)=max_sim.
// ---------------------------------------------------------------------------
__global__ __launch_bounds__(256) void finalize_kernel(
    const unsigned long long* __restrict__ packed,
    const float* __restrict__ sty_ss, float* __restrict__ out) {
  const int j = blockIdx.x * 256 + threadIdx.x;
  if (j >= A_DIM) return;
  const unsigned long long p = packed[j];
  const unsigned key = (unsigned)(p >> 32);
  const unsigned u = (key & 0x80000000u) ? (key ^ 0x80000000u) : ~key;
  const float v = __uint_as_float(u);
  const int idx = (int)(~(unsigned)(p & 0xFFFFFFFFu));
  out[j] = (float)idx;
  out[A_DIM + j] = v * (1.0f / sqrtf(sty_ss[j]));
}

extern "C" void kernel_launch(void* const* d_in, const int* in_sizes, int n_in,
                              void* d_out, int out_size, void* d_ws, size_t ws_size,
                              hipStream_t stream) {
  const float* model = (const float*)d_in[0];  // img side
  const float* style = (const float*)d_in[1];  // sty side
  float* out = (float*)d_out;
  char* ws = (char*)d_ws;

  const size_t usz = (size_t)A_DIM * L_DIM * 2;  // one f16 matrix: 37,748,736 B
  _Float16* img_hi = (_Float16*)(ws);
  _Float16* img_lo = (_Float16*)(ws + usz);
  _Float16* sty_hi = (_Float16*)(ws + 2 * usz);
  _Float16* sty_lo = (_Float16*)(ws + 3 * usz);
  float* img_ss = (float*)(ws + 4 * usz);        // zeroed accumulators
  float* sty_ss = img_ss + A_DIM;
  unsigned long long* packed = (unsigned long long*)(img_ss + 2 * A_DIM);

  // zero ss accumulators (2*A*4 B) + packed (A*8 B) in one contiguous memset
  hipMemsetAsync(img_ss, 0, (size_t)A_DIM * 16, stream);
  prep_kernel<<<dim3(CH / CPB, H_DIM / 3, 2), 256, 0, stream>>>(
      model, style, img_hi, img_lo, sty_hi, sty_lo, img_ss, sty_ss);
  gemm_max_kernel<<<dim3(A_DIM / BN, A_DIM / BM), 256, 0, stream>>>(
      sty_hi, sty_lo, img_hi, img_lo, img_ss, packed);
  finalize_kernel<<<18, 256, 0, stream>>>(packed, sty_ss, out);
}